// Round 25
// baseline (40.210 us; speedup 1.0000x reference)
//
#include <hip/hip_runtime.h>
#include <hip/hip_fp16.h>
#include <math.h>
#include <stdint.h>

#define U 50
#define TT 100
#define BB 256
#define LOG2E 1.44269504088896340736f

typedef _Float16 half2v __attribute__((ext_vector_type(2)));

__device__ __forceinline__ float dot2_acc(uint32_t h2, uint32_t w2, float c) {
#if __has_builtin(__builtin_amdgcn_fdot2)
    return __builtin_amdgcn_fdot2(__builtin_bit_cast(half2v, h2),
                                  __builtin_bit_cast(half2v, w2), c, false);
#else
    half2v a = __builtin_bit_cast(half2v, h2);
    half2v b = __builtin_bit_cast(half2v, w2);
    return fmaf((float)a.x, (float)b.x, fmaf((float)a.y, (float)b.y, c));
#endif
}

__device__ __forceinline__ float exp2_fast(float x) {
#if __has_builtin(__builtin_amdgcn_exp2f)
    return __builtin_amdgcn_exp2f(x);
#else
    return exp2f(x);
#endif
}

__device__ __forceinline__ float rcp_fast(float x) {
#if __has_builtin(__builtin_amdgcn_rcpf)
    return __builtin_amdgcn_rcpf(x);
#else
    return 1.0f / x;
#endif
}

__device__ __forceinline__ float tanh_fast(float x) {
    float e = __expf(2.0f * x);
    return fmaf(-2.0f, rcp_fast(e + 1.0f), 1.0f);   // saturates cleanly
}
__device__ __forceinline__ float param_act(float x, float mn, float mx) {
    float scale = 0.5f * (mx - mn);
    return tanh_fast(x) * scale + mn + scale;
}

// lgkm-only barrier: no vmcnt drain in the loop -> the global x prefetch
// stays in flight across barriers (round-14 lesson, now load-bearing).
#define BAR() do {                                            \
    asm volatile("s_waitcnt lgkmcnt(0)" ::: "memory");        \
    __builtin_amdgcn_s_barrier();                             \
    asm volatile("" ::: "memory");                            \
} while (0)

// Round-23 champion + LDS-pipe cuts:
// FOUR waves per batch; wave w owns gate w (0=i,1=f,2=g,3=o) of unit l
// (25 packed f16 weight dwords/lane, log2e-prescaled). One lgkm-only
// barrier per step; SoA conflict-free zex; redundant c/h on all waves;
// v_rcp + raw exp2 nonlinearities; cstate carries the tanh prescale.
// NEW: (1) x read from GLOBAL (L1-resident, prefetched 1 step ahead; rides
// across the lgkm-only barrier) -- xlds removed, one fewer LDS op/wave/step;
// (2) per-wave h buffers h16w[4][64] -- no 4-wave same-address writes, each
// wave's h write->reload is purely own-wave; (3) 8 dot2 chains (dep depth 4).
__global__ __launch_bounds__(256, 1) void encoder_kernel(
    const float* __restrict__ x,        // (B,T,4)
    const float* __restrict__ state,    // (B,T,4)
    const float* __restrict__ kernel,   // (4,200)
    const float* __restrict__ rec,      // (50,200)
    const float* __restrict__ bias,     // (200,)
    const float* __restrict__ w_dv, const float* __restrict__ b_dv,
    const float* __restrict__ w_dt, const float* __restrict__ b_dt,
    const float* __restrict__ w_mj, const float* __restrict__ b_mj,
    const float* __restrict__ w_ma, const float* __restrict__ b_ma,
    const float* __restrict__ w_mi, const float* __restrict__ b_mi,
    float* __restrict__ out)            // act_seq (B*T) then idm (B*5)
{
    const int b   = blockIdx.x;
    const int tid = threadIdx.x;
    const int w   = tid >> 6;           // gate owned by this wave (0..3)
    const int l   = tid & 63;
    const int cl  = (l < U) ? l : (U - 1);

    __shared__ __align__(16) _Float16 h16w[4][64];   // per-wave h copies
    __shared__ float zex[2][4][64];                  // dbuf SoA nonlinearities
    __shared__ float idm[8];

    // gate-specific prescale: sigmoid gates need exp(-z) = exp2(-log2e*z);
    // tanh gate needs exp(2z) = exp2(2*log2e*z).
    const float S = (w == 2) ? (2.0f * LOG2E) : LOG2E;

    // ---- per-lane weights: gate w, column cl -- 25 packed dwords (scaled) ----
    uint32_t wpk[25];
    #pragma unroll
    for (int j = 0; j < 25; ++j) {
        float r0 = rec[(2 * j) * 200 + w * U + cl] * S;
        float r1 = rec[(2 * j + 1) * 200 + w * U + cl] * S;
        half2v p; p.x = (_Float16)r0; p.y = (_Float16)r1;
        wpk[j] = __builtin_bit_cast(uint32_t, p);
    }
    #pragma unroll
    for (int j = 0; j < 25; ++j) asm volatile("" : "+v"(wpk[j]));

    float kc[4];
    #pragma unroll
    for (int f = 0; f < 4; ++f) kc[f] = kernel[f * 200 + w * U + cl] * S;
    float bz = bias[w * U + cl] * S;

    // ---- init per-wave h buffers (no x staging needed anymore) ----
    if (l < 64) h16w[w][l] = (_Float16)0.0f;
    __syncthreads();

    float cstate = 0.0f;                // carries 2*log2e * c (prescaled)
    uint32_t hvu[25];
    #pragma unroll
    for (int j = 0; j < 25; ++j) hvu[j] = 0u;   // h(0) = 0

    const uint4* __restrict__ hq = (const uint4*)&h16w[w][0];
    const uint32_t* __restrict__ hd = (const uint32_t*)&h16w[w][0];
    const float4* __restrict__ xg = (const float4*)(x + (size_t)b * TT * 4);

    float4 x4 = xg[0];                  // L1-resident after first block touch

    #pragma unroll 4
    for (int t = 0; t < TT; ++t) {
        const int buf = t & 1;
        // prefetch x(t+1) from global: VMEM, rides across the lgkm-only BAR
        float4 x4n = xg[(t + 1 < TT) ? (t + 1) : t];

        // z' (prescaled) for this wave's gate: x-part + 25 dot2 (8 chains)
        float z = fmaf(x4.x, kc[0], fmaf(x4.y, kc[1],
                  fmaf(x4.z, kc[2], fmaf(x4.w, kc[3], bz))));
        float a0 = 0.f, a1 = 0.f, a2 = 0.f, a3 = 0.f;
        float a4 = 0.f, a5 = 0.f, a6 = 0.f, a7 = 0.f;
        #pragma unroll
        for (int j = 0; j < 24; j += 8) {
            a0 = dot2_acc(hvu[j],     wpk[j],     a0);
            a1 = dot2_acc(hvu[j + 1], wpk[j + 1], a1);
            a2 = dot2_acc(hvu[j + 2], wpk[j + 2], a2);
            a3 = dot2_acc(hvu[j + 3], wpk[j + 3], a3);
            a4 = dot2_acc(hvu[j + 4], wpk[j + 4], a4);
            a5 = dot2_acc(hvu[j + 5], wpk[j + 5], a5);
            a6 = dot2_acc(hvu[j + 6], wpk[j + 6], a6);
            a7 = dot2_acc(hvu[j + 7], wpk[j + 7], a7);
        }
        a0 = dot2_acc(hvu[24], wpk[24], a0);
        z += ((a0 + a1) + (a2 + a3)) + ((a4 + a5) + (a6 + a7));

        // own gate's nonlinearity via raw exp2 + v_rcp. Wave 0 (i-gate)
        // stores 2*log2e * sigmoid so cstate is prescaled for tanh.
        float nl;
        if (w == 2)      nl = fmaf(-2.0f, rcp_fast(exp2_fast(z) + 1.0f), 1.0f);
        else if (w == 0) nl = (2.0f * LOG2E) * rcp_fast(1.0f + exp2_fast(-z));
        else             nl = rcp_fast(1.0f + exp2_fast(-z));
        zex[buf][w][l] = nl;                 // stride-4B write: conflict-free

        BAR();                               // lgkm-only: zex(t) visible

        // reads first: 4x b32 issue back-to-back (latency overlapped)
        float gi = zex[buf][0][l];           // pre-scaled by 2*log2e
        float gf = zex[buf][1][l];
        float gg = zex[buf][2][l];
        float go = zex[buf][3][l];
        cstate = fmaf(gf, cstate, gi * gg);  // = 2*log2e * c(t)
        float e  = exp2_fast(cstate);        // exp(2c)
        float r  = rcp_fast(e + 1.0f);
        float go2 = go + go;                 // off the serial chain
        float hn = fmaf(-go2, r, go);        // go * tanh(c)
        if (l < U) h16w[w][l] = (_Float16)hn;   // own-wave buffer only

        // reload packed h(t+1) from own buffer (own-wave order via lgkmcnt)
        #pragma unroll
        for (int q = 0; q < 6; ++q) {
            uint4 v = hq[q];
            hvu[4 * q + 0] = v.x; hvu[4 * q + 1] = v.y;
            hvu[4 * q + 2] = v.z; hvu[4 * q + 3] = v.w;
        }
        hvu[24] = hd[24];
        x4 = x4n;
        // next iteration writes zex[(t+1)&1] -- the OTHER buffer, so the
        // single barrier suffices.
    }

    // ---- 5 output heads (threads 0..4 are in wave 0; use its h buffer) ----
    if (tid < 5) {
        const float* wv = (tid == 0) ? w_dv : (tid == 1) ? w_dt :
                          (tid == 2) ? w_mj : (tid == 3) ? w_ma : w_mi;
        const float* bv = (tid == 0) ? b_dv : (tid == 1) ? b_dt :
                          (tid == 2) ? b_mj : (tid == 3) ? b_ma : b_mi;
        float s = bv[0];
        #pragma unroll
        for (int j = 0; j < U; ++j) s = fmaf((float)h16w[0][j], wv[j], s);
        float v;
        if (tid == 0)      v = param_act(s, 15.0f, 35.0f);
        else if (tid == 1) v = param_act(s, 0.5f, 3.0f);
        else if (tid == 2) v = fmaxf(s, 0.0f);
        else if (tid == 3) v = param_act(s, 0.5f, 3.0f);
        else               v = param_act(s, 0.5f, 4.0f);
        idm[tid] = v;
        out[BB * TT + b * 5 + tid] = v;
    }
    __syncthreads();

    // ---- IDM physics over T (256 threads) ----
    const float desired_v    = idm[0];
    const float desired_tgap = idm[1];
    const float min_jamx     = idm[2];
    const float max_act      = idm[3];
    const float min_act      = idm[4];
    const float inv_tsab = 1.0f / (2.0f * sqrtf(max_act * min_act));
    const float inv_dv   = 1.0f / desired_v;

    const float4* __restrict__ sb4 = (const float4*)(state + (size_t)b * TT * 4);
    for (int t = tid; t < TT; t += 256) {
        float4 s4 = sb4[t];
        float vel = s4.x;
        float dv  = s4.z;
        float dx  = s4.w;
        float dgap = fmaf(desired_tgap, vel, fmaf(vel * dv, inv_tsab, min_jamx));
        float r1 = vel * inv_dv;
        r1 = r1 * r1;
        r1 = r1 * r1;            // ^4
        float r2 = dgap / dx;
        r2 = r2 * r2;            // ^2
        out[b * TT + t] = max_act * (1.0f - (r1 + r2));
    }
}

extern "C" void kernel_launch(void* const* d_in, const int* in_sizes, int n_in,
                              void* d_out, int out_size, void* d_ws, size_t ws_size,
                              hipStream_t stream) {
    const float* x      = (const float*)d_in[0];
    const float* state  = (const float*)d_in[1];
    const float* kern   = (const float*)d_in[2];
    const float* rec    = (const float*)d_in[3];
    const float* bias   = (const float*)d_in[4];
    const float* w_dv   = (const float*)d_in[5];
    const float* b_dv   = (const float*)d_in[6];
    const float* w_dt   = (const float*)d_in[7];
    const float* b_dt   = (const float*)d_in[8];
    const float* w_mj   = (const float*)d_in[9];
    const float* b_mj   = (const float*)d_in[10];
    const float* w_ma   = (const float*)d_in[11];
    const float* b_ma   = (const float*)d_in[12];
    const float* w_mi   = (const float*)d_in[13];
    const float* b_mi   = (const float*)d_in[14];
    float* out = (float*)d_out;

    encoder_kernel<<<BB, 256, 0, stream>>>(
        x, state, kern, rec, bias,
        w_dv, b_dv, w_dt, b_dt, w_mj, b_mj, w_ma, b_ma, w_mi, b_mi,
        out);
}

// Round 26
// 37.510 us; speedup vs baseline: 1.0720x; 1.0720x over previous
//
#include <hip/hip_runtime.h>
#include <hip/hip_fp16.h>
#include <math.h>
#include <stdint.h>

#define U 50
#define TT 100
#define BB 256
#define LOG2E 1.44269504088896340736f

typedef _Float16 half2v __attribute__((ext_vector_type(2)));

__device__ __forceinline__ float dot2_acc(uint32_t h2, uint32_t w2, float c) {
#if __has_builtin(__builtin_amdgcn_fdot2)
    return __builtin_amdgcn_fdot2(__builtin_bit_cast(half2v, h2),
                                  __builtin_bit_cast(half2v, w2), c, false);
#else
    half2v a = __builtin_bit_cast(half2v, h2);
    half2v b = __builtin_bit_cast(half2v, w2);
    return fmaf((float)a.x, (float)b.x, fmaf((float)a.y, (float)b.y, c));
#endif
}

__device__ __forceinline__ float exp2_fast(float x) {
#if __has_builtin(__builtin_amdgcn_exp2f)
    return __builtin_amdgcn_exp2f(x);
#else
    return exp2f(x);
#endif
}

// Single v_rcp_f32 (1 ulp) instead of the IEEE div expansion (~9 serial ops)
// hipcc emits for 1.0f/x without -ffast-math.
__device__ __forceinline__ float rcp_fast(float x) {
#if __has_builtin(__builtin_amdgcn_rcpf)
    return __builtin_amdgcn_rcpf(x);
#else
    return 1.0f / x;
#endif
}

__device__ __forceinline__ float tanh_fast(float x) {
    float e = __expf(2.0f * x);
    return fmaf(-2.0f, rcp_fast(e + 1.0f), 1.0f);   // saturates cleanly
}
__device__ __forceinline__ float param_act(float x, float mn, float mx) {
    float scale = 0.5f * (mx - mn);
    return tanh_fast(x) * scale + mn + scale;
}

// lgkm-only barrier: no vmcnt drain in the loop (round-14 lesson).
#define BAR() do {                                            \
    asm volatile("s_waitcnt lgkmcnt(0)" ::: "memory");        \
    __builtin_amdgcn_s_barrier();                             \
    asm volatile("" ::: "memory");                            \
} while (0)

// CHAMPION (round 23, 37.5 us): FOUR waves per batch; wave w owns gate w
// (0=i,1=f,2=g,3=o) of unit l (25 packed f16 weight dwords/lane,
// log2e-prescaled). One lgkm-only barrier per step; SoA conflict-free zex;
// redundant c/h on all waves; x pre-staged in LDS -> ZERO VMEM in the loop
// (round-24 lesson: a per-step global x read exposes vmcnt on the serial
// path, +13%); v_rcp + raw exp2 nonlinearities; cstate carries the tanh
// prescale; 4 dot2 chains; unroll-4.
__global__ __launch_bounds__(256, 1) void encoder_kernel(
    const float* __restrict__ x,        // (B,T,4)
    const float* __restrict__ state,    // (B,T,4)
    const float* __restrict__ kernel,   // (4,200)
    const float* __restrict__ rec,      // (50,200)
    const float* __restrict__ bias,     // (200,)
    const float* __restrict__ w_dv, const float* __restrict__ b_dv,
    const float* __restrict__ w_dt, const float* __restrict__ b_dt,
    const float* __restrict__ w_mj, const float* __restrict__ b_mj,
    const float* __restrict__ w_ma, const float* __restrict__ b_ma,
    const float* __restrict__ w_mi, const float* __restrict__ b_mi,
    float* __restrict__ out)            // act_seq (B*T) then idm (B*5)
{
    const int b   = blockIdx.x;
    const int tid = threadIdx.x;
    const int w   = tid >> 6;           // gate owned by this wave (0..3)
    const int l   = tid & 63;
    const int cl  = (l < U) ? l : (U - 1);

    __shared__ __align__(16) float4 xlds[TT];        // staged x(b,:,:)  1600B
    __shared__ __align__(16) _Float16 h16[64];       // h state (f16)
    __shared__ float zex[2][4][64];                  // dbuf SoA nonlinearities
    __shared__ float idm[8];

    // gate-specific prescale: sigmoid gates need exp(-z) = exp2(-log2e*z);
    // tanh gate needs exp(2z) = exp2(2*log2e*z).
    const float S = (w == 2) ? (2.0f * LOG2E) : LOG2E;

    // ---- per-lane weights: gate w, column cl -- 25 packed dwords (scaled) ----
    uint32_t wpk[25];
    #pragma unroll
    for (int j = 0; j < 25; ++j) {
        float r0 = rec[(2 * j) * 200 + w * U + cl] * S;
        float r1 = rec[(2 * j + 1) * 200 + w * U + cl] * S;
        half2v p; p.x = (_Float16)r0; p.y = (_Float16)r1;
        wpk[j] = __builtin_bit_cast(uint32_t, p);
    }
    #pragma unroll
    for (int j = 0; j < 25; ++j) asm volatile("" : "+v"(wpk[j]));

    float kc[4];
    #pragma unroll
    for (int f = 0; f < 4; ++f) kc[f] = kernel[f * 200 + w * U + cl] * S;
    float bz = bias[w * U + cl] * S;

    // ---- stage x into LDS, init h (full sync once) ----
    const float4* __restrict__ xg = (const float4*)(x + (size_t)b * TT * 4);
    if (tid < TT) xlds[tid] = xg[tid];
    if (tid < 64) h16[tid] = (_Float16)0.0f;
    __syncthreads();

    float cstate = 0.0f;                // carries 2*log2e * c (prescaled)
    uint32_t hvu[25];
    #pragma unroll
    for (int j = 0; j < 25; ++j) hvu[j] = 0u;   // h(0) = 0

    const uint4* __restrict__ hq = (const uint4*)h16;
    const uint32_t* __restrict__ hd = (const uint32_t*)h16;

    #pragma unroll 4
    for (int t = 0; t < TT; ++t) {
        const int buf = t & 1;
        float4 x4 = xlds[t];   // broadcast ds_read_b128

        // z' (prescaled) for this wave's gate: x-part + 25 dot2 (4 chains)
        float z = fmaf(x4.x, kc[0], fmaf(x4.y, kc[1],
                  fmaf(x4.z, kc[2], fmaf(x4.w, kc[3], bz))));
        float a0 = 0.f, a1 = 0.f, a2 = 0.f, a3 = 0.f;
        #pragma unroll
        for (int j = 0; j < 24; j += 4) {
            a0 = dot2_acc(hvu[j],     wpk[j],     a0);
            a1 = dot2_acc(hvu[j + 1], wpk[j + 1], a1);
            a2 = dot2_acc(hvu[j + 2], wpk[j + 2], a2);
            a3 = dot2_acc(hvu[j + 3], wpk[j + 3], a3);
        }
        a0 = dot2_acc(hvu[24], wpk[24], a0);
        z += (a0 + a1) + (a2 + a3);

        // own gate's nonlinearity via raw exp2 + v_rcp (no IEEE div).
        // Wave 0 (i-gate) stores 2*log2e * sigmoid so cstate is prescaled
        // for the post-barrier tanh.
        float nl;
        if (w == 2)      nl = fmaf(-2.0f, rcp_fast(exp2_fast(z) + 1.0f), 1.0f);
        else if (w == 0) nl = (2.0f * LOG2E) * rcp_fast(1.0f + exp2_fast(-z));
        else             nl = rcp_fast(1.0f + exp2_fast(-z));
        zex[buf][w][l] = nl;                 // stride-4B write: conflict-free

        BAR();                               // lgkm-only: zex(t) visible

        // reads first: 4x b32 issue back-to-back (latency overlapped)
        float gi = zex[buf][0][l];           // pre-scaled by 2*log2e
        float gf = zex[buf][1][l];
        float gg = zex[buf][2][l];
        float go = zex[buf][3][l];
        cstate = fmaf(gf, cstate, gi * gg);  // = 2*log2e * c(t)
        float e  = exp2_fast(cstate);        // exp(2c)
        float r  = rcp_fast(e + 1.0f);
        float go2 = go + go;                 // off the serial chain
        float hn = fmaf(-go2, r, go);        // go * tanh(c)
        if (l < U) h16[l] = (_Float16)hn;    // 4x same-value write: benign

        // reload packed h(t+1); own-wave write->read is in-order (lgkmcnt);
        // completion is drained inside the next BAR's lgkmcnt(0).
        #pragma unroll
        for (int q = 0; q < 6; ++q) {
            uint4 v = hq[q];
            hvu[4 * q + 0] = v.x; hvu[4 * q + 1] = v.y;
            hvu[4 * q + 2] = v.z; hvu[4 * q + 3] = v.w;
        }
        hvu[24] = hd[24];
        // next iteration writes zex[(t+1)&1] -- the OTHER buffer, so the
        // single barrier suffices.
    }

    // ---- 5 output heads (threads 0..4; wave 0 wrote h16 itself) ----
    if (tid < 5) {
        const float* wv = (tid == 0) ? w_dv : (tid == 1) ? w_dt :
                          (tid == 2) ? w_mj : (tid == 3) ? w_ma : w_mi;
        const float* bv = (tid == 0) ? b_dv : (tid == 1) ? b_dt :
                          (tid == 2) ? b_mj : (tid == 3) ? b_ma : b_mi;
        float s = bv[0];
        #pragma unroll
        for (int j = 0; j < U; ++j) s = fmaf((float)h16[j], wv[j], s);
        float v;
        if (tid == 0)      v = param_act(s, 15.0f, 35.0f);
        else if (tid == 1) v = param_act(s, 0.5f, 3.0f);
        else if (tid == 2) v = fmaxf(s, 0.0f);
        else if (tid == 3) v = param_act(s, 0.5f, 3.0f);
        else               v = param_act(s, 0.5f, 4.0f);
        idm[tid] = v;
        out[BB * TT + b * 5 + tid] = v;
    }
    __syncthreads();

    // ---- IDM physics over T (256 threads) ----
    const float desired_v    = idm[0];
    const float desired_tgap = idm[1];
    const float min_jamx     = idm[2];
    const float max_act      = idm[3];
    const float min_act      = idm[4];
    const float inv_tsab = 1.0f / (2.0f * sqrtf(max_act * min_act));
    const float inv_dv   = 1.0f / desired_v;

    const float4* __restrict__ sb4 = (const float4*)(state + (size_t)b * TT * 4);
    for (int t = tid; t < TT; t += 256) {
        float4 s4 = sb4[t];
        float vel = s4.x;
        float dv  = s4.z;
        float dx  = s4.w;
        float dgap = fmaf(desired_tgap, vel, fmaf(vel * dv, inv_tsab, min_jamx));
        float r1 = vel * inv_dv;
        r1 = r1 * r1;
        r1 = r1 * r1;            // ^4
        float r2 = dgap / dx;
        r2 = r2 * r2;            // ^2
        out[b * TT + t] = max_act * (1.0f - (r1 + r2));
    }
}

extern "C" void kernel_launch(void* const* d_in, const int* in_sizes, int n_in,
                              void* d_out, int out_size, void* d_ws, size_t ws_size,
                              hipStream_t stream) {
    const float* x      = (const float*)d_in[0];
    const float* state  = (const float*)d_in[1];
    const float* kern   = (const float*)d_in[2];
    const float* rec    = (const float*)d_in[3];
    const float* bias   = (const float*)d_in[4];
    const float* w_dv   = (const float*)d_in[5];
    const float* b_dv   = (const float*)d_in[6];
    const float* w_dt   = (const float*)d_in[7];
    const float* b_dt   = (const float*)d_in[8];
    const float* w_mj   = (const float*)d_in[9];
    const float* b_mj   = (const float*)d_in[10];
    const float* w_ma   = (const float*)d_in[11];
    const float* b_ma   = (const float*)d_in[12];
    const float* w_mi   = (const float*)d_in[13];
    const float* b_mi   = (const float*)d_in[14];
    float* out = (float*)d_out;

    encoder_kernel<<<BB, 256, 0, stream>>>(
        x, state, kern, rec, bias,
        w_dv, b_dv, w_dt, b_dt, w_mj, b_mj, w_ma, b_ma, w_mi, b_mi,
        out);
}